// Round 1
// baseline (247.015 us; speedup 1.0000x reference)
//
#include <hip/hip_runtime.h>
#include <math.h>

// LIF recurrence: v_t = v_{t-1}*decay*(1-z_{t-1}) + x_t ; z_t = (v_t > 0.3)
// x [B=128,T=2048,H=128] f32; out [B,T,H] f32 spikes.
//
// R4: wave-specialized producer/consumer, 256 blocks x 256 threads (4 waves).
//   wave0   : computes the block's 64 serial chains (register-double-buffered
//             LDS reads: batch of 16 x values prefetched one chain-batch ahead,
//             so the ~120cy ds_read latency hides under the ~200cy VALU chain).
//   wave1/2 : DMA producers. global_load_lds only on their vmcnt -> counted
//             s_waitcnt vmcnt(16) (never 0 mid-loop): 32KB of loads stay in
//             flight ACROSS barriers (kills the __syncthreads vmcnt(0) drain
//             that quantized R3 to ~5us/tile).
//   wave3   : z flusher. LDS->reg->global dwordx4; stores isolated on its own
//             vmcnt so they never gate the load pipeline.
// One raw s_barrier per tile. Compute wave drains lgkmcnt(0) only (z writes
// must be visible to wave3 after the barrier).
//
// Ring hazard ledger (buf m, NBUF=4): filled@iter m-2 (after B_{m-2}),
// computed@iter m (loads guaranteed done at B_m by wave1/2's counted wait in
// iter m-1), z-flushed@iter m+1 (ds_reads retire before wave3's stores issue,
// hence before B_{m+2}), refilled as tile m+4 @iter m+2 (after B_{m+2}). Safe.

constexpr int Bdim = 128;
constexpr int Tdim = 2048;
constexpr int Hdim = 128;
constexpr int HW   = 64;          // chains per block
constexpr int U    = 128;         // timesteps per tile (32 KB)
constexpr int NBUF = 4;           // LDS ring depth (128 KB)
constexpr int NTILE = Tdim / U;   // 16
constexpr float VTH = 0.3f;

typedef const __attribute__((address_space(1))) void* gptr_t;
typedef __attribute__((address_space(3))) void* lptr_t;

#define BAR()     asm volatile("s_barrier" ::: "memory")
#define WAITV16() asm volatile("s_waitcnt vmcnt(16)" ::: "memory")
#define WAITV0()  asm volatile("s_waitcnt vmcnt(0)" ::: "memory")
#define WAITL0()  asm volatile("s_waitcnt lgkmcnt(0)" ::: "memory")

__global__ __launch_bounds__(256) void lif_kernel(
    const float* __restrict__ x,
    const float* __restrict__ v0,
    const float* __restrict__ z0,
    const float* __restrict__ decay_raw,
    float* __restrict__ out)
{
    __shared__ float lds[NBUF][U][HW];

    const int tid  = threadIdx.x;
    const int wave = tid >> 6;
    const int lane = tid & 63;
    const int blk  = blockIdx.x;          // 0..255
    const int b    = blk >> 1;
    const int h0   = (blk & 1) * HW;

    const float* xbase = x   + (size_t)b * Tdim * Hdim + h0;
    float*       obase = out + (size_t)b * Tdim * Hdim + h0;

    // DMA inst jj covers tile rows [4jj,4jj+4): lane i -> row 4jj+(i>>4),
    // col (i&15)*4. HW writes lane i at lds_base + i*16 B. Matches layout.
    const int sub = (lane >> 4) * Hdim + (lane & 15) * 4;

    // waves 1,2 split the tile's 32 DMA insts (16 each -> 2 DMA queues,
    // counted waits stay <= 32 outstanding per wave).
    auto fill = [&](int tile, int buf) {
        const float* g = xbase + (size_t)tile * U * Hdim + sub;
        #pragma unroll
        for (int q = 0; q < 16; ++q) {
            const int jj = (wave - 1) * 16 + q;
            __builtin_amdgcn_global_load_lds(
                (gptr_t)(const void*)(g + (size_t)(4 * jj) * Hdim),
                (lptr_t)(void*)&lds[buf][4 * jj][0],
                16, 0, 0);
        }
    };

    // wave 3: z tile -> global, 32 x dwordx4 (1 KB per inst)
    auto flush = [&](int tile, int buf) {
        #pragma unroll
        for (int s = 0; s < 32; ++s) {
            const int row = 4 * s + (lane >> 4);
            const int col = (lane & 15) * 4;
            const float4 vv = *(const float4*)&lds[buf][row][col];
            *(float4*)(obase + (size_t)(tile * U + row) * Hdim + col) = vv;
        }
    };

    float decay = 0.f, v = 0.f, z = 0.f;
    if (wave == 0) {
        decay = 1.0f / (1.0f + expf(-decay_raw[h0 + lane]));
        v = v0[b * Hdim + h0 + lane];
        z = z0[b * Hdim + h0 + lane];
    } else if (wave <= 2) {
        fill(0, 0);
        fill(1, 1);
        WAITV16();                         // tile 0 resident; tile 1 in flight
    }
    BAR();

    for (int k = 0; k < NTILE; ++k) {
        if (wave == 0) {
            const int cb = k & 3;
            // register-double-buffered serial loop: prefetch batch g+1 while
            // running the dependent chain on batch g. All indexing static
            // under full unroll (no scratch, rule #20).
            float xa[16], xb[16];
            #pragma unroll
            for (int j = 0; j < 16; ++j) xa[j] = lds[cb][j][lane];
            #pragma unroll
            for (int g = 0; g < 8; ++g) {
                if (g < 7) {
                    #pragma unroll
                    for (int j = 0; j < 16; ++j) {
                        const float t = lds[cb][(g + 1) * 16 + j][lane];
                        if (g & 1) xa[j] = t; else xb[j] = t;
                    }
                }
                #pragma unroll
                for (int j = 0; j < 16; ++j) {
                    const float xv = (g & 1) ? xb[j] : xa[j];
                    const float vd = v * decay;
                    v = ((z > 0.5f) ? 0.0f : vd) + xv;   // exact: z in {0,1}
                    z = (v > VTH) ? 1.0f : 0.0f;
                    lds[cb][g * 16 + j][lane] = z;       // overwrite consumed x
                }
            }
            WAITL0();                      // z writes visible before barrier
        } else if (wave <= 2) {
            if (k + 2 < NTILE) {
                fill(k + 2, (k + 2) & 3);
                WAITV16();                 // tile k+1 done; tile k+2 in flight
            } else {
                WAITV0();                  // tail: drain last tile's loads
            }
        } else {
            if (k >= 1) flush(k - 1, (k - 1) & 3);
        }
        BAR();
    }
    if (wave == 3) flush(NTILE - 1, (NTILE - 1) & 3);   // final z tile
}

extern "C" void kernel_launch(void* const* d_in, const int* in_sizes, int n_in,
                              void* d_out, int out_size, void* d_ws, size_t ws_size,
                              hipStream_t stream) {
    const float* x         = (const float*)d_in[0];
    const float* v0        = (const float*)d_in[1];
    const float* z0        = (const float*)d_in[2];
    const float* decay_raw = (const float*)d_in[3];
    float* out = (float*)d_out;

    lif_kernel<<<Bdim * Hdim / HW, 256, 0, stream>>>(x, v0, z0, decay_raw, out);
}

// Round 2
// 244.900 us; speedup vs baseline: 1.0086x; 1.0086x over previous
//
#include <hip/hip_runtime.h>
#include <math.h>

// LIF recurrence: v_t = v_{t-1}*decay*(1-z_{t-1}) + x_t ; z_t = (v_t > 0.3)
// x [B=128,T=2048,H=128] f32; out [B,T,H] f32 spikes.
//
// R5: kill the LDS round-trip in the serial loop (R3/R4 post-mortem: ~103
// cyc/step came from per-step ds_read/ds_write to the SAME buffer -> compiler
// alias fences expose full LDS latency every step).
//   256 blocks x 2 waves:
//   wave0: x loaded DIRECTLY global->VGPR (coalesced 256B/wave dword loads),
//          3-group (48-step) software lookahead in a 4x16 static register
//          rotation; serial chain fully in registers; z written to a DEDICATED
//          LDS buffer (never read in the loop -> no alias fences).
//   wave1: warms L2 with tile k+2's lines (same lines wave0 reads; no extra
//          HBM traffic), then flushes tile k-1's z (LDS transpose -> dwordx4).
//   One raw s_barrier per 128-step tile; z double-buffered (64 KB LDS).
//
// Hazards: wave1 reads zs[(k-1)&1] while wave0 writes zs[k&1] (disjoint).
// Wave0 re-writes buffer (k+1)&1 only after BAR(k), which wave1 reaches only
// after its flush(k-1) ds_reads retired (data consumed by stores). Safe.

constexpr int Bdim = 128;
constexpr int Tdim = 2048;
constexpr int Hdim = 128;
constexpr int HW   = 64;          // chains per block
constexpr int U    = 128;         // timesteps per tile
constexpr int NTILE = Tdim / U;   // 16
constexpr float VTH = 0.3f;

#define BAR()    asm volatile("s_barrier" ::: "memory")
#define WAITL0() asm volatile("s_waitcnt lgkmcnt(0)" ::: "memory")

__global__ __launch_bounds__(128) void lif_kernel(
    const float* __restrict__ x,
    const float* __restrict__ v0,
    const float* __restrict__ z0,
    const float* __restrict__ decay_raw,
    float* __restrict__ out)
{
    __shared__ float zs[2][U][HW];

    const int tid  = threadIdx.x;
    const int wave = tid >> 6;
    const int lane = tid & 63;
    const int blk  = blockIdx.x;          // 0..255
    const int b    = blk >> 1;
    const int h0   = (blk & 1) * HW;

    const float* xbase = x   + (size_t)b * Tdim * Hdim + h0;
    float*       obase = out + (size_t)b * Tdim * Hdim + h0;

    if (wave == 0) {
        // ---- compute wave: 64 serial chains, x global->reg, z -> LDS ----
        const float* xl = xbase + lane;                  // lane's own channel
        const float decay = 1.0f / (1.0f + expf(-decay_raw[h0 + lane]));
        float v = v0[b * Hdim + h0 + lane];
        float z = z0[b * Hdim + h0 + lane];

        float xq[4][16];                                 // static-indexed -> regs
        #pragma unroll
        for (int q = 0; q < 3; ++q)                      // prologue: groups 0..2
            #pragma unroll
            for (int j = 0; j < 16; ++j)
                xq[q][j] = xl[(size_t)(q * 16 + j) * Hdim];

        for (int k = 0; k < NTILE; ++k) {
            float* zcol = &zs[k & 1][0][lane];
            #pragma unroll
            for (int g = 0; g < 8; ++g) {
                // issue loads for flat group i+3 (3 groups = 48 steps ahead)
                if (k * 8 + g + 3 < 8 * NTILE) {         // uniform branch
                    const size_t t3 = (size_t)(k * 8 + g + 3) * 16;
                    #pragma unroll
                    for (int j = 0; j < 16; ++j)
                        xq[(g + 3) & 3][j] = xl[(t3 + j) * Hdim];
                }
                // 16-step dependent chain on group g (all registers)
                #pragma unroll
                for (int j = 0; j < 16; ++j) {
                    const float xv = xq[g & 3][j];
                    const float vd = v * decay;
                    v = ((z > 0.5f) ? 0.0f : vd) + xv;   // exact: z in {0,1}
                    z = (v > VTH) ? 1.0f : 0.0f;
                    zcol[(g * 16 + j) * HW] = z;         // dedicated z buffer
                }
            }
            WAITL0();                                    // z visible to wave1
            BAR();
        }
    } else {
        // ---- service wave: L2 warm (k+2) + z flush (k-1) ----
        const int col = (lane & 15) * 4;
        const int rb  = lane >> 4;
        const int sub = rb * Hdim + col;
        float4 acc = make_float4(0.f, 0.f, 0.f, 0.f);    // keeps prefetch live

        for (int k = 0; k < NTILE; ++k) {
            if (k + 2 < NTILE) {                         // warm tile k+2
                const float* p = xbase + (size_t)(k + 2) * U * Hdim + sub;
                #pragma unroll
                for (int s = 0; s < 32; ++s) {
                    const float4 t = *(const float4*)(p + (size_t)(4 * s) * Hdim);
                    acc.x += t.x; acc.y += t.y; acc.z += t.z; acc.w += t.w;
                }
            }
            if (k >= 1) {                                // flush tile k-1
                const int tt = k - 1;
                #pragma unroll
                for (int s = 0; s < 32; ++s) {
                    const int row = 4 * s + rb;
                    const float4 vv = *(const float4*)&zs[tt & 1][row][col];
                    *(float4*)(obase + (size_t)(tt * U + row) * Hdim + col) = vv;
                }
            }
            BAR();
        }
        {                                                // final z tile
            const int tt = NTILE - 1;
            #pragma unroll
            for (int s = 0; s < 32; ++s) {
                const int row = 4 * s + rb;
                const float4 vv = *(const float4*)&zs[tt & 1][row][col];
                *(float4*)(obase + (size_t)(tt * U + row) * Hdim + col) = vv;
            }
        }
        asm volatile("" :: "v"(acc.x), "v"(acc.y), "v"(acc.z), "v"(acc.w));
    }
}

extern "C" void kernel_launch(void* const* d_in, const int* in_sizes, int n_in,
                              void* d_out, int out_size, void* d_ws, size_t ws_size,
                              hipStream_t stream) {
    const float* x         = (const float*)d_in[0];
    const float* v0        = (const float*)d_in[1];
    const float* z0        = (const float*)d_in[2];
    const float* decay_raw = (const float*)d_in[3];
    float* out = (float*)d_out;

    lif_kernel<<<Bdim * Hdim / HW, 128, 0, stream>>>(x, v0, z0, decay_raw, out);
}